// Round 6
// baseline (978.310 us; speedup 1.0000x reference)
//
#include <hip/hip_runtime.h>
#include <hip/hip_bf16.h>
#include <math.h>

#define S_ 2048
#define D_ 1024
#define H_ 4
#define HD_ 256
#define B_ 4

typedef __hip_bfloat16 bf16;
typedef short s16x8 __attribute__((ext_vector_type(8)));
typedef float f32x4 __attribute__((ext_vector_type(4)));

// async global->LDS, 16B per lane; LDS dest is wave-uniform base + lane*16
#define GLOAD16(g, l)                                             \
    __builtin_amdgcn_global_load_lds(                             \
        (const __attribute__((address_space(1))) void*)(g),       \
        (__attribute__((address_space(3))) void*)(l), 16, 0, 0)

static __device__ inline short bfb(float x) {
    bf16 t = __float2bfloat16(x);
    short s;
    __builtin_memcpy(&s, &t, 2);
    return s;
}

// ---------------------------------------------------------------------------
// MFMA NT GEMM: C[m,n] = sum_k A[m,k]*B[n,k], A/B bf16 row-major.
// 128x128 tile, BK=32, 256 threads = 4 waves (2x2), each wave 4x4 frags of
// 16x16x32 bf16 MFMA. M,N multiples of 128; K multiple of 32.
// z decomposed: zb = z/zdiv, zh = z%zdiv; per-operand (b,h) strides in elems.
// MODE: 0 = fp32 store, 1 = bf16 store, 3 = fp32 store + legal-bias (h=zh,
//       bias batch = bbase + zb).
// LDS slot swizzle (verified-neutral, verified-correct, kept from R3).
// ---------------------------------------------------------------------------
template <int MODE>
__global__ __launch_bounds__(256) void mfma_nt(
    int K,
    const bf16* __restrict__ A, int lda, long sA_b, long sA_h,
    const bf16* __restrict__ Bm, int ldb, long sB_b, long sB_h,
    void* __restrict__ Cp, int ldc, long sC_b, long sC_h,
    int zdiv, int bbase,
    const double* __restrict__ mag1d, const double* __restrict__ v3d,
    const double* __restrict__ meand, const float* __restrict__ bias_sc)
{
    __shared__ __align__(16) short As[128 * 32];
    __shared__ __align__(16) short Bs[128 * 32];

    const int tid = threadIdx.x;
    const int w = tid >> 6, lane = tid & 63;
    const int srow = lane >> 2;                          // staging: 16 rows/inst
    const int scol = (((lane & 3) ^ (srow & 3)) << 3);   // pre-swizzled source col
    const int quad = lane >> 4, r = lane & 15;           // mfma fragment coords
    const int qx = quad ^ (r & 3);                       // swizzled read slot
    const int wr = (w >> 1) * 64, wc = (w & 1) * 64;     // wave's 64x64 quadrant
    const int zb = blockIdx.z / zdiv, zh = blockIdx.z % zdiv;

    const bf16* Ap = A + (size_t)zb * sA_b + (size_t)zh * sA_h +
                     (size_t)blockIdx.y * 128 * lda;
    const bf16* Bp = Bm + (size_t)zb * sB_b + (size_t)zh * sB_h +
                     (size_t)blockIdx.x * 128 * ldb;

    f32x4 acc[4][4] = {};

    for (int k0 = 0; k0 < K; k0 += 32) {
        if (k0) __syncthreads();  // previous compute done before LDS overwrite
#pragma unroll
        for (int l = 0; l < 2; l++) {
            GLOAD16(Ap + (size_t)(w * 32 + l * 16 + srow) * lda + (k0 + scol),
                    &As[(w * 32 + l * 16) * 32]);
            GLOAD16(Bp + (size_t)(w * 32 + l * 16 + srow) * ldb + (k0 + scol),
                    &Bs[(w * 32 + l * 16) * 32]);
        }
        __syncthreads();  // drains vmcnt (compiler emits waitcnt before barrier)

        s16x8 af[4], bfv[4];
        const s16x8* A8 = (const s16x8*)As;
        const s16x8* B8 = (const s16x8*)Bs;
#pragma unroll
        for (int i = 0; i < 4; i++) af[i] = A8[(wr + i * 16 + r) * 4 + qx];
#pragma unroll
        for (int j = 0; j < 4; j++) bfv[j] = B8[(wc + j * 16 + r) * 4 + qx];
#pragma unroll
        for (int i = 0; i < 4; i++)
#pragma unroll
            for (int j = 0; j < 4; j++)
                acc[i][j] = __builtin_amdgcn_mfma_f32_16x16x32_bf16(
                    af[i], bfv[j], acc[i][j], 0, 0, 0);
    }

    // C/D layout: col = lane&15, row = quad*4 + reg   [m89-verified]
    const int row0 = blockIdx.y * 128 + wr + quad * 4;
    const int col0 = blockIdx.x * 128 + wc + r;

    if (MODE == 0) {
        float* C = (float*)Cp + (size_t)zb * sC_b + (size_t)zh * sC_h;
#pragma unroll
        for (int i = 0; i < 4; i++)
#pragma unroll
            for (int j = 0; j < 4; j++)
#pragma unroll
                for (int p = 0; p < 4; p++)
                    C[(size_t)(row0 + i * 16 + p) * ldc + (col0 + j * 16)] = acc[i][j][p];
    } else if (MODE == 1) {
        bf16* C = (bf16*)Cp + (size_t)zb * sC_b + (size_t)zh * sC_h;
#pragma unroll
        for (int i = 0; i < 4; i++)
#pragma unroll
            for (int j = 0; j < 4; j++)
#pragma unroll
                for (int p = 0; p < 4; p++)
                    C[(size_t)(row0 + i * 16 + p) * ldc + (col0 + j * 16)] =
                        __float2bfloat16(acc[i][j][p]);
    } else {  // MODE 3: scores + legal bias; h = zh, batch = bbase + zb
        float* C = (float*)Cp + (size_t)zb * sC_b + (size_t)zh * sC_h;
        const int h = zh;
        const int bbatch = bbase + zb;
        const float bsc = bias_sc[h];
        if (h == 0) {  // causal triu(k=1)
#pragma unroll
            for (int i = 0; i < 4; i++)
#pragma unroll
                for (int j = 0; j < 4; j++)
#pragma unroll
                    for (int p = 0; p < 4; p++) {
                        const int rr = row0 + i * 16 + p, c = col0 + j * 16;
                        C[(size_t)rr * ldc + c] = acc[i][j][p] + ((c > rr) ? bsc : 0.0f);
                    }
        } else if (h == 2) {  // proximity
#pragma unroll
            for (int i = 0; i < 4; i++)
#pragma unroll
                for (int j = 0; j < 4; j++)
#pragma unroll
                    for (int p = 0; p < 4; p++) {
                        const int rr = row0 + i * 16 + p, c = col0 + j * 16;
                        int d = c - rr; d = d < 0 ? -d : d;
                        C[(size_t)rr * ldc + c] =
                            acc[i][j][p] + bsc * expf(-(float)d * (1.0f / 2048.0f));
                    }
        } else {  // h==1 intent (> mean) / h==3 violation (> 0.5), exact fp64 compare
            const double* src = (h == 1) ? mag1d : v3d;
            const double thr = (h == 1) ? meand[0] : 0.5;
            double rv[16], cv[4];
#pragma unroll
            for (int i = 0; i < 4; i++)
#pragma unroll
                for (int p = 0; p < 4; p++)
                    rv[i * 4 + p] = src[(size_t)bbatch * S_ + row0 + i * 16 + p];
#pragma unroll
            for (int j = 0; j < 4; j++)
                cv[j] = src[(size_t)bbatch * S_ + col0 + j * 16];
#pragma unroll
            for (int i = 0; i < 4; i++)
#pragma unroll
                for (int j = 0; j < 4; j++)
#pragma unroll
                    for (int p = 0; p < 4; p++) {
                        const int rr = row0 + i * 16 + p, c = col0 + j * 16;
                        C[(size_t)rr * ldc + c] =
                            acc[i][j][p] + ((rv[i * 4 + p] * cv[j] > thr) ? bsc : 0.0f);
                    }
        }
    }
}

// ---------------------------------------------------------------------------
// Fused softmax + P.V for one batch b (replaces softmax_fused + mfma_pv).
// Grid 128 blocks x 512 threads (8 waves). Block owns 16 score rows
// (r0 = blk*16) for ALL 4 heads:
//   pass 1: stream rows (L3-hot), exact row max + exp-sum -> m[h], inv[h]
//   K-loop (64 x 32-col steps):
//     - each thread recomputes ONE weight per head: w = exp(s-m)*inv
//       (identical values to the old softmax_fused -> P bf16 identical)
//     - writes the 16x32 P-subtile to double-buffered LDS (8 KB total)
//     - avgw (required output) written directly; rowsum accumulated
//     - lgkmcnt(0) + raw s_barrier (NO vmcnt drain -> global loads flow on)
//     - per wave, per head: A-frag from LDS, 2 V B-frags DIRECT from
//       global/L2 (V = 4 MB/b, shared by all blocks, L2-hot), 2 MFMA
// P is never materialized in HBM: kills the 128 MB write + ~92 MB re-fetch
// and the entire 70-100us mfma_pv dispatch.
// ---------------------------------------------------------------------------
__global__ __launch_bounds__(512) void fused_smpv(
    const float* __restrict__ scores,  // [H][S][S] fp32, this b
    const bf16* __restrict__ Vt,       // [H][B][HD][S] base
    int b,
    bf16* __restrict__ Cc,             // concat + b*S*D
    float* __restrict__ avgw_b,        // avgw + b*S*S
    float* __restrict__ rowsum_b)      // rowsum + b*S
{
    __shared__ __align__(16) short Pb[2][4][16 * 32];  // 8 KB

    const int tid = threadIdx.x;
    const int rr = tid >> 5;           // 0..15 row within block
    const int c32 = tid & 31;          // 0..31 col lane within row
    const int r0 = blockIdx.x * 16;

    const int w = tid >> 6, lane = tid & 63;
    const int quad = lane >> 4, r = lane & 15;
    const int n0 = w * 32;             // wave's 32-col slice of the 256 e-dims

    const bf16* vh[4];
#pragma unroll
    for (int h = 0; h < 4; h++)
        vh[h] = Vt + ((size_t)h * B_ + b) * HD_ * S_;

    const float* sp[4];
#pragma unroll
    for (int h = 0; h < 4; h++)
        sp[h] = scores + ((size_t)h * S_ + r0 + rr) * S_;

    // ---- pass 1: exact row max + exp-sum per (row, head) ----
    float mh[4], inv[4];
#pragma unroll
    for (int h = 0; h < 4; h++) {
        const float4* rp4 = (const float4*)sp[h];
        float4 v[16];
#pragma unroll
        for (int j = 0; j < 16; j++) v[j] = rp4[c32 + j * 32];
        float m = -1e30f;
#pragma unroll
        for (int j = 0; j < 16; j++) {
            m = fmaxf(m, fmaxf(fmaxf(v[j].x, v[j].y), fmaxf(v[j].z, v[j].w)));
        }
#pragma unroll
        for (int d = 16; d; d >>= 1) m = fmaxf(m, __shfl_xor(m, d, 32));
        float s = 0.f;
#pragma unroll
        for (int j = 0; j < 16; j++) {
            s += expf(v[j].x - m);
            s += expf(v[j].y - m);
            s += expf(v[j].z - m);
            s += expf(v[j].w - m);
        }
#pragma unroll
        for (int d = 16; d; d >>= 1) s += __shfl_xor(s, d, 32);
        mh[h] = m;
        inv[h] = 1.0f / s;
    }

    // ---- K-loop: recompute w, tiny LDS P-tile, MFMA vs direct-L2 V ----
    f32x4 acc[4][2] = {};
    float rs = 0.f;
    float sv[4], svn[4];
#pragma unroll
    for (int h = 0; h < 4; h++) sv[h] = sp[h][c32];

#pragma unroll 1
    for (int t = 0; t < 64; ++t) {
        const int k0 = t * 32;
        const int buf = t & 1;
        float wacc = 0.f;
#pragma unroll
        for (int h = 0; h < 4; h++) {
            const float wv = expf(sv[h] - mh[h]) * inv[h];
            wacc += wv;
            Pb[buf][h][rr * 32 + c32] = bfb(wv);
        }
        const float aw = wacc * 0.25f;
        avgw_b[(size_t)(r0 + rr) * S_ + k0 + c32] = aw;
        rs += aw;
        // prefetch next step's scores before the barrier (hides L3 latency)
        const int kn = (t < 63) ? k0 + 32 : k0;
#pragma unroll
        for (int h = 0; h < 4; h++) svn[h] = sp[h][kn + c32];

        asm volatile("s_waitcnt lgkmcnt(0)" ::: "memory");  // my P writes done
        __builtin_amdgcn_s_barrier();                       // raw: no vmcnt drain
        __builtin_amdgcn_sched_barrier(0);                  // pin ds_reads below

#pragma unroll
        for (int h = 0; h < 4; h++) {
            const s16x8 af = *(const s16x8*)&Pb[buf][h][r * 32 + quad * 8];
            const s16x8 b0 =
                *(const s16x8*)(vh[h] + (size_t)(n0 + r) * S_ + k0 + quad * 8);
            const s16x8 b1 =
                *(const s16x8*)(vh[h] + (size_t)(n0 + 16 + r) * S_ + k0 + quad * 8);
            acc[h][0] = __builtin_amdgcn_mfma_f32_16x16x32_bf16(af, b0, acc[h][0], 0, 0, 0);
            acc[h][1] = __builtin_amdgcn_mfma_f32_16x16x32_bf16(af, b1, acc[h][1], 0, 0, 0);
        }
        // Pb[buf] rewritten at t+2, after barrier(t+1): all waves' reads done.
#pragma unroll
        for (int h = 0; h < 4; h++) sv[h] = svn[h];
    }

#pragma unroll
    for (int d = 16; d; d >>= 1) rs += __shfl_xor(rs, d, 32);
    if (c32 == 0) rowsum_b[r0 + rr] = rs;

    // C/D layout: col = lane&15, row = quad*4 + reg
#pragma unroll
    for (int h = 0; h < 4; h++)
#pragma unroll
        for (int j = 0; j < 2; j++)
#pragma unroll
            for (int p = 0; p < 4; p++)
                Cc[(size_t)(r0 + quad * 4 + p) * D_ + h * HD_ + n0 + j * 16 + r] =
                    __float2bfloat16(acc[h][j][p]);
}

// fp32 -> bf16 (optionally scaled), 4 elems/thread
__global__ __launch_bounds__(256) void cvt_bf16(const float* __restrict__ in,
                                                bf16* __restrict__ out, int n,
                                                float scale) {
    const size_t i0 = ((size_t)blockIdx.x * 256 + threadIdx.x) * 4;
    if (i0 + 3 < (size_t)n) {
        const float4 v = *(const float4*)(in + i0);
        out[i0 + 0] = __float2bfloat16(v.x * scale);
        out[i0 + 1] = __float2bfloat16(v.y * scale);
        out[i0 + 2] = __float2bfloat16(v.z * scale);
        out[i0 + 3] = __float2bfloat16(v.w * scale);
    }
}

// Vraw [H, B*S, hd] -> Vt [H, B, hd, S]  (64x64 bf16 LDS tile transpose)
__global__ __launch_bounds__(256) void transpose_v(const bf16* __restrict__ in,
                                                   bf16* __restrict__ out) {
    const int h = blockIdx.z / B_, b = blockIdx.z % B_;
    const int e0 = blockIdx.x * 64, s0 = blockIdx.y * 64;
    __shared__ short t[64][66];
    const int tid = threadIdx.x;
    const int rr = tid >> 2;            // 0..63
    const int cc = (tid & 3) << 4;      // 0,16,32,48
    const bf16* ip = in + (((size_t)h * B_ * S_) + (size_t)b * S_ + s0) * HD_ + e0;
    const s16x8 v0 = *(const s16x8*)(ip + (size_t)rr * HD_ + cc);
    const s16x8 v1 = *(const s16x8*)(ip + (size_t)rr * HD_ + cc + 8);
#pragma unroll
    for (int i = 0; i < 8; i++) {
        t[rr][cc + i] = v0[i];
        t[rr][cc + 8 + i] = v1[i];
    }
    __syncthreads();
    bf16* op = out + (((size_t)h * B_ + b) * HD_ + e0 + rr) * S_ + s0 + cc;
    s16x8 o0, o1;
#pragma unroll
    for (int i = 0; i < 8; i++) {
        o0[i] = t[cc + i][rr];
        o1[i] = t[cc + 8 + i][rr];
    }
    *(s16x8*)op = o0;
    *(s16x8*)(op + 8) = o1;
}

// mag1[b,s] = ||emb[b,s,256:512]|| (fp64), v3[b,s] = emb[b,s,1023]
__global__ __launch_bounds__(256) void prep_kernel(const float* __restrict__ emb,
                                                   double* __restrict__ mag1d,
                                                   double* __restrict__ v3d) {
    const long row = blockIdx.x;
    const int tid = threadIdx.x;
    const float x = emb[row * D_ + 256 + tid];
    __shared__ double red[256];
    red[tid] = (double)x * (double)x;
    __syncthreads();
    for (int off = 128; off > 0; off >>= 1) {
        if (tid < off) red[tid] += red[tid + off];
        __syncthreads();
    }
    if (tid == 0) {
        mag1d[row] = sqrt(red[0]);
        v3d[row] = (double)emb[row * D_ + 1023];
    }
}

__global__ __launch_bounds__(256) void mean_kernel(const double* __restrict__ mag1d,
                                                   double* __restrict__ meand) {
    const int tid = threadIdx.x;
    __shared__ double red[256];
    double acc = 0.0;
    for (int b = 0; b < B_; b++) {
        double ss = 0.0;
        for (int i = tid; i < S_; i += 256) ss += mag1d[(long)b * S_ + i];
        __syncthreads();
        red[tid] = ss;
        __syncthreads();
        for (int off = 128; off > 0; off >>= 1) {
            if (tid < off) red[tid] += red[tid + off];
            __syncthreads();
        }
        if (tid == 0) {
            const double rb = red[0] / (double)S_;
            acc += rb * rb;
        }
        __syncthreads();
    }
    if (tid == 0) meand[0] = acc / (double)B_;
}

// y = proj + Wo_b + emb; LayerNorm(y) in place (float4-vectorized)
__global__ __launch_bounds__(256) void ln_kernel(float* __restrict__ out,
                                                 const float* __restrict__ emb,
                                                 const float* __restrict__ wob,
                                                 const float* __restrict__ g,
                                                 const float* __restrict__ beta) {
    const long row = blockIdx.x;
    float* o = out + row * D_;
    const float* e = emb + row * D_;
    const int tid = threadIdx.x;
    __shared__ float red[256];
    const float4 vo = ((const float4*)o)[tid];
    const float4 vw = ((const float4*)wob)[tid];
    const float4 ve = ((const float4*)e)[tid];
    float v[4] = {vo.x + vw.x + ve.x, vo.y + vw.y + ve.y,
                  vo.z + vw.z + ve.z, vo.w + vw.w + ve.w};
    red[tid] = v[0] + v[1] + v[2] + v[3];
    __syncthreads();
    for (int off = 128; off > 0; off >>= 1) {
        if (tid < off) red[tid] += red[tid + off];
        __syncthreads();
    }
    const float mu = red[0] * (1.0f / 1024.0f);
    __syncthreads();
    float vs = 0.0f;
#pragma unroll
    for (int i = 0; i < 4; i++) {
        const float d = v[i] - mu;
        vs += d * d;
    }
    red[tid] = vs;
    __syncthreads();
    for (int off = 128; off > 0; off >>= 1) {
        if (tid < off) red[tid] += red[tid + off];
        __syncthreads();
    }
    const float var = red[0] * (1.0f / 1024.0f);
    const float inv = 1.0f / sqrtf(var + 1e-5f);
    const float4 g4 = ((const float4*)g)[tid];
    const float4 b4 = ((const float4*)beta)[tid];
    float4 r4;
    r4.x = (v[0] - mu) * inv * g4.x + b4.x;
    r4.y = (v[1] - mu) * inv * g4.y + b4.y;
    r4.z = (v[2] - mu) * inv * g4.z + b4.z;
    r4.w = (v[3] - mu) * inv * g4.w + b4.w;
    ((float4*)o)[tid] = r4;
}

__global__ __launch_bounds__(256) void guilt_kernel(const float* __restrict__ rowsum,
                                                    float* __restrict__ guilt) {
    const int b = blockIdx.x, tid = threadIdx.x;
    const float* r = rowsum + (long)b * S_;
    float* gq = guilt + (long)b * S_;
    __shared__ float red[256];
    float v[8];
    float m = -1e30f;
#pragma unroll
    for (int i = 0; i < 8; i++) {
        v[i] = r[tid + 256 * i];
        m = fmaxf(m, v[i]);
    }
    red[tid] = m;
    __syncthreads();
    for (int off = 128; off > 0; off >>= 1) {
        if (tid < off) red[tid] = fmaxf(red[tid], red[tid + off]);
        __syncthreads();
    }
    m = red[0];
    __syncthreads();
    float sum = 0.0f;
#pragma unroll
    for (int i = 0; i < 8; i++) {
        v[i] = expf(v[i] - m);
        sum += v[i];
    }
    red[tid] = sum;
    __syncthreads();
    for (int off = 128; off > 0; off >>= 1) {
        if (tid < off) red[tid] += red[tid + off];
        __syncthreads();
    }
    const float inv = 1.0f / red[0];
#pragma unroll
    for (int i = 0; i < 8; i++) gq[tid + 256 * i] = v[i] * inv;
}

extern "C" void kernel_launch(void* const* d_in, const int* in_sizes, int n_in,
                              void* d_out, int out_size, void* d_ws, size_t ws_size,
                              hipStream_t stream) {
    const float* emb = (const float*)d_in[0];
    const float* Wq = (const float*)d_in[1];
    const float* Wk = (const float*)d_in[2];
    const float* Wv = (const float*)d_in[3];
    const float* bias_sc = (const float*)d_in[4];
    const float* Wo_w = (const float*)d_in[5];
    const float* Wo_b = (const float*)d_in[6];
    const float* ln_g = (const float*)d_in[7];
    const float* ln_bt = (const float*)d_in[8];

    char* ws = (char*)d_ws;
    size_t off = 0;
    auto alloc = [&](size_t bytes) {
        size_t o = off;
        off = (off + bytes + 255) & ~(size_t)255;
        return o;
    };
    bf16* embb = (bf16*)(ws + alloc((size_t)B_ * S_ * D_ * 2));
    bf16* concat = embb;  // alias: embb dead after QKV GEMMs, concat written later
    bf16* Qm = (bf16*)(ws + alloc((size_t)H_ * B_ * S_ * HD_ * 2));  // [H,B*S,hd]
    bf16* Km = (bf16*)(ws + alloc((size_t)H_ * B_ * S_ * HD_ * 2));
    bf16* Vtb = (bf16*)(ws + alloc((size_t)H_ * B_ * HD_ * S_ * 2)); // [H,B,hd,S]
    bf16* Wqb = (bf16*)(ws + alloc((size_t)H_ * HD_ * HD_ * 2));
    bf16* Wkb = (bf16*)(ws + alloc((size_t)H_ * HD_ * HD_ * 2));
    bf16* Wvb = (bf16*)(ws + alloc((size_t)H_ * HD_ * HD_ * 2));
    bf16* Wob = (bf16*)(ws + alloc((size_t)D_ * D_ * 2));
    double* mag1d = (double*)(ws + alloc((size_t)B_ * S_ * 8));
    double* v3d = (double*)(ws + alloc((size_t)B_ * S_ * 8));
    double* meand = (double*)(ws + alloc(256));
    float* rowsum = (float*)(ws + alloc((size_t)B_ * S_ * 4));
    float* scores = (float*)(ws + alloc((size_t)H_ * S_ * S_ * 4));  // one b
    bf16* Vraw = (bf16*)scores;  // alias: Vraw consumed (transposed) before scores b=0

    float* outp = (float*)d_out;
    float* avgw = outp + (size_t)B_ * S_ * D_;
    float* guilt = avgw + (size_t)B_ * S_ * S_;

    // casts (Q-scale 1/16 folded into Wq)
    cvt_bf16<<<(B_ * S_ * D_) / 1024, 256, 0, stream>>>(emb, embb, B_ * S_ * D_, 1.0f);
    cvt_bf16<<<(H_ * HD_ * HD_) / 1024, 256, 0, stream>>>(Wq, Wqb, H_ * HD_ * HD_, 0.0625f);
    cvt_bf16<<<(H_ * HD_ * HD_) / 1024, 256, 0, stream>>>(Wk, Wkb, H_ * HD_ * HD_, 1.0f);
    cvt_bf16<<<(H_ * HD_ * HD_) / 1024, 256, 0, stream>>>(Wv, Wvb, H_ * HD_ * HD_, 1.0f);
    cvt_bf16<<<(D_ * D_) / 1024, 256, 0, stream>>>(Wo_w, Wob, D_ * D_, 1.0f);

    prep_kernel<<<B_ * S_, 256, 0, stream>>>(emb, mag1d, v3d);
    mean_kernel<<<1, 256, 0, stream>>>(mag1d, meand);

    // QKV projections: MFMA, M = B*S (=8192), N = hd, K = hd, z = head
    {
        const dim3 g(HD_ / 128, (B_ * S_) / 128, H_);
        const long sQ = (long)B_ * S_ * HD_;
        mfma_nt<1><<<g, 256, 0, stream>>>(HD_, embb, D_, 0, HD_,
                                          Wqb, HD_, 0, (long)HD_ * HD_,
                                          Qm, HD_, 0, sQ, H_, 0,
                                          nullptr, nullptr, nullptr, nullptr);
        mfma_nt<1><<<g, 256, 0, stream>>>(HD_, embb, D_, 0, HD_,
                                          Wkb, HD_, 0, (long)HD_ * HD_,
                                          Km, HD_, 0, sQ, H_, 0,
                                          nullptr, nullptr, nullptr, nullptr);
        mfma_nt<1><<<g, 256, 0, stream>>>(HD_, embb, D_, 0, HD_,
                                          Wvb, HD_, 0, (long)HD_ * HD_,
                                          Vraw, HD_, 0, sQ, H_, 0,
                                          nullptr, nullptr, nullptr, nullptr);
    }
    transpose_v<<<dim3(HD_ / 64, S_ / 64, H_ * B_), 256, 0, stream>>>(Vraw, Vtb);

    for (int b = 0; b < B_; b++) {
        // scores[h,s,t] = Q.K^T + bias  (fp32 out, per-b buffer stays L3-warm)
        mfma_nt<3><<<dim3(S_ / 128, S_ / 128, H_), 256, 0, stream>>>(
            HD_,
            Qm + (size_t)b * S_ * HD_, HD_, 0, (long)B_ * S_ * HD_,
            Km + (size_t)b * S_ * HD_, HD_, 0, (long)B_ * S_ * HD_,
            scores, S_, 0, (long)S_ * S_,
            H_, b, mag1d, v3d, meand, bias_sc);
        // fused softmax + P.V: no P materialization, avgw/rowsum/concat direct
        fused_smpv<<<S_ / 16, 512, 0, stream>>>(
            scores, Vtb, b,
            concat + (size_t)b * S_ * D_,
            avgw + (size_t)b * S_ * S_,
            rowsum + (size_t)b * S_);
    }

    // out = concat @ Wo^T (MFMA, bf16 Wo)
    mfma_nt<0><<<dim3(D_ / 128, (B_ * S_) / 128, 1), 256, 0, stream>>>(
        D_, concat, D_, 0, 0, Wob, D_, 0, 0, outp, D_, 0, 0,
        1, 0, nullptr, nullptr, nullptr, nullptr);

    ln_kernel<<<B_ * S_, 256, 0, stream>>>(outp, emb, Wo_b, ln_g, ln_bt);
    guilt_kernel<<<B_, 256, 0, stream>>>(rowsum, guilt);
}

// Round 7
// 510.223 us; speedup vs baseline: 1.9174x; 1.9174x over previous
//
#include <hip/hip_runtime.h>
#include <hip/hip_bf16.h>
#include <math.h>

#define S_ 2048
#define D_ 1024
#define H_ 4
#define HD_ 256
#define B_ 4

typedef __hip_bfloat16 bf16;
typedef short s16x8 __attribute__((ext_vector_type(8)));
typedef short s16x4 __attribute__((ext_vector_type(4)));
typedef float f32x4 __attribute__((ext_vector_type(4)));

// async global->LDS, 16B per lane; LDS dest is wave-uniform base + lane*16
#define GLOAD16(g, l)                                             \
    __builtin_amdgcn_global_load_lds(                             \
        (const __attribute__((address_space(1))) void*)(g),       \
        (__attribute__((address_space(3))) void*)(l), 16, 0, 0)

// counted-vmcnt wait + raw barrier (does NOT drain vmcnt) + scheduling fence
#define WAITB(N)                                              \
    asm volatile("s_waitcnt vmcnt(" #N ")" ::: "memory");     \
    __builtin_amdgcn_s_barrier();                             \
    __builtin_amdgcn_sched_barrier(0);

static __device__ inline short bfb(float x) {
    bf16 t = __float2bfloat16(x);
    short s;
    __builtin_memcpy(&s, &t, 2);
    return s;
}

// ---------------------------------------------------------------------------
// MFMA NT GEMM: C[m,n] = sum_k A[m,k]*B[n,k], A/B bf16 row-major.
// 128x128 tile, BK=32, 256 threads = 4 waves (2x2), each wave 4x4 frags of
// 16x16x32 bf16 MFMA. M,N multiples of 128; K multiple of 64 (NT >= 2).
//
// R7: counted-vmcnt pipeline (ported from the verified mfma_pv loop):
// 3 LDS buffer pairs (48 KB), depth-2 prefetch, per K-step:
//   s_waitcnt vmcnt(4)  <- tile t's 4 loads done, tile t+1's stay in flight
//   raw s_barrier        <- no drain
//   stage(t+2)           <- overwrites buf((t+2)%3); its readers (compute t-1)
//                           finished before the barrier above
//   compute(t)
// Epilogue drains 4 -> 0. Same MFMA order as the R2 kernel -> bit-identical.
//
// z decomposed: zb = z/zdiv, zh = z%zdiv; per-operand (b,h) strides in elems.
// MODE: 0 = fp32 store, 1 = bf16 store, 3 = fp32 store + legal-bias.
// LDS slot swizzle (verified-correct, kept from R3): scol/qx XOR pair.
// ---------------------------------------------------------------------------
template <int MODE>
__global__ __launch_bounds__(256) void mfma_nt(
    int K,
    const bf16* __restrict__ A, int lda, long sA_b, long sA_h,
    const bf16* __restrict__ Bm, int ldb, long sB_b, long sB_h,
    void* __restrict__ Cp, int ldc, long sC_b, long sC_h,
    int zdiv, int bbase,
    const double* __restrict__ mag1d, const double* __restrict__ v3d,
    const double* __restrict__ meand, const float* __restrict__ bias_sc)
{
    __shared__ __align__(16) short As[3][128 * 32];
    __shared__ __align__(16) short Bs[3][128 * 32];

    const int tid = threadIdx.x;
    const int w = tid >> 6, lane = tid & 63;
    const int srow = lane >> 2;                          // staging: 16 rows/inst
    const int scol = (((lane & 3) ^ (srow & 3)) << 3);   // pre-swizzled source col
    const int quad = lane >> 4, r = lane & 15;           // mfma fragment coords
    const int qx = quad ^ (r & 3);                       // swizzled read slot
    const int wr = (w >> 1) * 64, wc = (w & 1) * 64;     // wave's 64x64 quadrant
    const int zb = blockIdx.z / zdiv, zh = blockIdx.z % zdiv;

    const bf16* Ap = A + (size_t)zb * sA_b + (size_t)zh * sA_h +
                     (size_t)blockIdx.y * 128 * lda;
    const bf16* Bp = Bm + (size_t)zb * sB_b + (size_t)zh * sB_h +
                     (size_t)blockIdx.x * 128 * ldb;

    f32x4 acc[4][4] = {};

    auto stage = [&](int bs, int k0) {
#pragma unroll
        for (int l = 0; l < 2; l++) {
            GLOAD16(Ap + (size_t)(w * 32 + l * 16 + srow) * lda + (k0 + scol),
                    &As[bs][(w * 32 + l * 16) * 32]);
            GLOAD16(Bp + (size_t)(w * 32 + l * 16 + srow) * ldb + (k0 + scol),
                    &Bs[bs][(w * 32 + l * 16) * 32]);
        }
    };
    auto compute = [&](int bs) {
        const s16x8* A8 = (const s16x8*)&As[bs][0];
        const s16x8* B8 = (const s16x8*)&Bs[bs][0];
        s16x8 af[4], bfv[4];
#pragma unroll
        for (int i = 0; i < 4; i++) af[i] = A8[(wr + i * 16 + r) * 4 + qx];
#pragma unroll
        for (int j = 0; j < 4; j++) bfv[j] = B8[(wc + j * 16 + r) * 4 + qx];
        __builtin_amdgcn_s_setprio(1);
#pragma unroll
        for (int i = 0; i < 4; i++)
#pragma unroll
            for (int j = 0; j < 4; j++)
                acc[i][j] = __builtin_amdgcn_mfma_f32_16x16x32_bf16(
                    af[i], bfv[j], acc[i][j], 0, 0, 0);
        __builtin_amdgcn_s_setprio(0);
    };

    const int NT = K >> 5;
    stage(0, 0);
    stage(1, 32);
    int cb = 0;
#pragma unroll 1
    for (int t = 0; t < NT - 2; ++t) {
        WAITB(4);
        int sb = cb + 2; if (sb >= 3) sb -= 3;
        stage(sb, (t + 2) * 32);
        compute(cb);
        cb = (cb == 2) ? 0 : cb + 1;
    }
    WAITB(4);
    compute(cb);
    cb = (cb == 2) ? 0 : cb + 1;
    WAITB(0);
    compute(cb);

    // C/D layout: col = lane&15, row = quad*4 + reg   [m89-verified]
    const int row0 = blockIdx.y * 128 + wr + quad * 4;
    const int col0 = blockIdx.x * 128 + wc + r;

    if (MODE == 0) {
        float* C = (float*)Cp + (size_t)zb * sC_b + (size_t)zh * sC_h;
#pragma unroll
        for (int i = 0; i < 4; i++)
#pragma unroll
            for (int j = 0; j < 4; j++)
#pragma unroll
                for (int p = 0; p < 4; p++)
                    C[(size_t)(row0 + i * 16 + p) * ldc + (col0 + j * 16)] = acc[i][j][p];
    } else if (MODE == 1) {
        bf16* C = (bf16*)Cp + (size_t)zb * sC_b + (size_t)zh * sC_h;
#pragma unroll
        for (int i = 0; i < 4; i++)
#pragma unroll
            for (int j = 0; j < 4; j++)
#pragma unroll
                for (int p = 0; p < 4; p++)
                    C[(size_t)(row0 + i * 16 + p) * ldc + (col0 + j * 16)] =
                        __float2bfloat16(acc[i][j][p]);
    } else {  // MODE 3: scores + legal bias; h = zh, batch = bbase + zb
        float* C = (float*)Cp + (size_t)zb * sC_b + (size_t)zh * sC_h;
        const int h = zh;
        const int bbatch = bbase + zb;
        const float bsc = bias_sc[h];
        if (h == 0) {  // causal triu(k=1)
#pragma unroll
            for (int i = 0; i < 4; i++)
#pragma unroll
                for (int j = 0; j < 4; j++)
#pragma unroll
                    for (int p = 0; p < 4; p++) {
                        const int rr = row0 + i * 16 + p, c = col0 + j * 16;
                        C[(size_t)rr * ldc + c] = acc[i][j][p] + ((c > rr) ? bsc : 0.0f);
                    }
        } else if (h == 2) {  // proximity
#pragma unroll
            for (int i = 0; i < 4; i++)
#pragma unroll
                for (int j = 0; j < 4; j++)
#pragma unroll
                    for (int p = 0; p < 4; p++) {
                        const int rr = row0 + i * 16 + p, c = col0 + j * 16;
                        int d = c - rr; d = d < 0 ? -d : d;
                        C[(size_t)rr * ldc + c] =
                            acc[i][j][p] + bsc * expf(-(float)d * (1.0f / 2048.0f));
                    }
        } else {  // h==1 intent (> mean) / h==3 violation (> 0.5), exact fp64 compare
            const double* src = (h == 1) ? mag1d : v3d;
            const double thr = (h == 1) ? meand[0] : 0.5;
            double rv[16], cv[4];
#pragma unroll
            for (int i = 0; i < 4; i++)
#pragma unroll
                for (int p = 0; p < 4; p++)
                    rv[i * 4 + p] = src[(size_t)bbatch * S_ + row0 + i * 16 + p];
#pragma unroll
            for (int j = 0; j < 4; j++)
                cv[j] = src[(size_t)bbatch * S_ + col0 + j * 16];
#pragma unroll
            for (int i = 0; i < 4; i++)
#pragma unroll
                for (int j = 0; j < 4; j++)
#pragma unroll
                    for (int p = 0; p < 4; p++) {
                        const int rr = row0 + i * 16 + p, c = col0 + j * 16;
                        C[(size_t)rr * ldc + c] =
                            acc[i][j][p] + ((rv[i * 4 + p] * cv[j] > thr) ? bsc : 0.0f);
                    }
        }
    }
}

// ---------------------------------------------------------------------------
// Dedicated batched P.V GEMM (R2/R3 verified 70us version, restored):
// C[b, s, h*HD + e] = sum_t P[b,h,s,t] * V[t,e].
// Tile 128x256, 512 threads = 8 waves (2Mx4N). Deep pipeline: 6 LDS buffers
// x 24 KB, prefetch depth 5, vmcnt(12) + raw barrier per step; epilogue
// drains 12->9->6->3->0. XCD-clustered (b,h) mapping keeps V panels L2-hot.
// ---------------------------------------------------------------------------
__global__ __launch_bounds__(512) void mfma_pv(const bf16* __restrict__ Pm,
                                               const bf16* __restrict__ Vt,
                                               bf16* __restrict__ Cc) {
    // per buffer: A 128x32 (4096 shorts) | B 256x32 (8192 shorts) = 24 KB
    __shared__ __align__(16) short L[6][12288];

    const int tid = threadIdx.x;
    const int w = tid >> 6, lane = tid & 63;
    const int quad = lane >> 4, r = lane & 15;
    const int qx = quad ^ (r & 3);                    // swizzled read slot
    const int wr = (w >> 2) * 64, wc = (w & 3) * 64;  // wave's 64x64 subtile

    const int bid = blockIdx.x;
    const int bh = (bid & 7) * 2 + ((bid >> 3) >> 4);  // 0..15, bijective
    const int rb = (bid >> 3) & 15;                    // row-block 0..15
    const int b = bh >> 2, h = bh & 3;

    const bf16* Ap = Pm + ((size_t)bh * S_ + (size_t)rb * 128) * S_;  // P rows
    const bf16* Bp = Vt + (size_t)(h * B_ + b) * HD_ * S_;            // V^T panel

    const int srow = tid >> 2;                          // 0..127
    const int scol = (((tid & 3) ^ (srow & 3)) << 3);   // pre-swizzled source col
    const int wbase = w * 512;                          // wave's 16-row LDS slab

    f32x4 acc[4][4] = {};

    auto stage = [&](int bs, int t) {
        short* sb = &L[bs][0];
        const int k0 = t * 32;
        GLOAD16(Ap + (size_t)srow * S_ + (k0 + scol), sb + wbase);
        GLOAD16(Bp + (size_t)srow * S_ + (k0 + scol), sb + 4096 + wbase);
        GLOAD16(Bp + (size_t)(128 + srow) * S_ + (k0 + scol), sb + 8192 + wbase);
    };
    auto compute = [&](int bs) {
        const s16x8* A8 = (const s16x8*)&L[bs][0];
        const s16x8* B8 = (const s16x8*)&L[bs][4096];
        s16x8 af[4], bfv[4];
#pragma unroll
        for (int i = 0; i < 4; i++) af[i] = A8[(wr + i * 16 + r) * 4 + qx];
#pragma unroll
        for (int j = 0; j < 4; j++) bfv[j] = B8[(wc + j * 16 + r) * 4 + qx];
        __builtin_amdgcn_s_setprio(1);
#pragma unroll
        for (int i = 0; i < 4; i++)
#pragma unroll
            for (int j = 0; j < 4; j++)
                acc[i][j] = __builtin_amdgcn_mfma_f32_16x16x32_bf16(
                    af[i], bfv[j], acc[i][j], 0, 0, 0);
        __builtin_amdgcn_s_setprio(0);
    };

    stage(0, 0); stage(1, 1); stage(2, 2); stage(3, 3); stage(4, 4);

    int cb = 0, sn = 5;  // compute / stage buffer indices (mod 6)
#pragma unroll 1
    for (int t = 0; t < 59; ++t) {  // NT=64; stages t+5 = 5..63
        WAITB(12);
        stage(sn, t + 5);
        compute(cb);
        cb = (cb == 5) ? 0 : cb + 1;
        sn = (sn == 5) ? 0 : sn + 1;
    }
    WAITB(12); compute(cb); cb = (cb == 5) ? 0 : cb + 1;
    WAITB(9);  compute(cb); cb = (cb == 5) ? 0 : cb + 1;
    WAITB(6);  compute(cb); cb = (cb == 5) ? 0 : cb + 1;
    WAITB(3);  compute(cb); cb = (cb == 5) ? 0 : cb + 1;
    WAITB(0);  compute(cb);

    const int row0 = rb * 128 + wr + quad * 4;
    const int col0 = h * HD_ + wc + r;
    bf16* C = Cc + (size_t)b * S_ * D_;
#pragma unroll
    for (int i = 0; i < 4; i++)
#pragma unroll
        for (int j = 0; j < 4; j++)
#pragma unroll
            for (int p = 0; p < 4; p++)
                C[(size_t)(row0 + i * 16 + p) * D_ + col0 + j * 16] =
                    __float2bfloat16(acc[i][j][p]);
}

// fp32 -> bf16 (optionally scaled), 4 elems/thread
__global__ __launch_bounds__(256) void cvt_bf16(const float* __restrict__ in,
                                                bf16* __restrict__ out, int n,
                                                float scale) {
    const size_t i0 = ((size_t)blockIdx.x * 256 + threadIdx.x) * 4;
    if (i0 + 3 < (size_t)n) {
        const float4 v = *(const float4*)(in + i0);
        out[i0 + 0] = __float2bfloat16(v.x * scale);
        out[i0 + 1] = __float2bfloat16(v.y * scale);
        out[i0 + 2] = __float2bfloat16(v.z * scale);
        out[i0 + 3] = __float2bfloat16(v.w * scale);
    }
}

// Vraw [H, B*S, hd] -> Vt [H, B, hd, S]  (64x64 bf16 LDS tile transpose)
__global__ __launch_bounds__(256) void transpose_v(const bf16* __restrict__ in,
                                                   bf16* __restrict__ out) {
    const int h = blockIdx.z / B_, b = blockIdx.z % B_;
    const int e0 = blockIdx.x * 64, s0 = blockIdx.y * 64;
    __shared__ short t[64][66];
    const int tid = threadIdx.x;
    const int rr = tid >> 2;            // 0..63
    const int cc = (tid & 3) << 4;      // 0,16,32,48
    const bf16* ip = in + (((size_t)h * B_ * S_) + (size_t)b * S_ + s0) * HD_ + e0;
    const s16x8 v0 = *(const s16x8*)(ip + (size_t)rr * HD_ + cc);
    const s16x8 v1 = *(const s16x8*)(ip + (size_t)rr * HD_ + cc + 8);
#pragma unroll
    for (int i = 0; i < 8; i++) {
        t[rr][cc + i] = v0[i];
        t[rr][cc + 8 + i] = v1[i];
    }
    __syncthreads();
    bf16* op = out + (((size_t)h * B_ + b) * HD_ + e0 + rr) * S_ + s0 + cc;
    s16x8 o0, o1;
#pragma unroll
    for (int i = 0; i < 8; i++) {
        o0[i] = t[cc + i][rr];
        o1[i] = t[cc + 8 + i][rr];
    }
    *(s16x8*)op = o0;
    *(s16x8*)(op + 8) = o1;
}

// mag1[b,s] = ||emb[b,s,256:512]|| (fp64), v3[b,s] = emb[b,s,1023]
__global__ __launch_bounds__(256) void prep_kernel(const float* __restrict__ emb,
                                                   double* __restrict__ mag1d,
                                                   double* __restrict__ v3d) {
    const long row = blockIdx.x;
    const int tid = threadIdx.x;
    const float x = emb[row * D_ + 256 + tid];
    __shared__ double red[256];
    red[tid] = (double)x * (double)x;
    __syncthreads();
    for (int off = 128; off > 0; off >>= 1) {
        if (tid < off) red[tid] += red[tid + off];
        __syncthreads();
    }
    if (tid == 0) {
        mag1d[row] = sqrt(red[0]);
        v3d[row] = (double)emb[row * D_ + 1023];
    }
}

__global__ __launch_bounds__(256) void mean_kernel(const double* __restrict__ mag1d,
                                                   double* __restrict__ meand) {
    const int tid = threadIdx.x;
    __shared__ double red[256];
    double acc = 0.0;
    for (int b = 0; b < B_; b++) {
        double ss = 0.0;
        for (int i = tid; i < S_; i += 256) ss += mag1d[(long)b * S_ + i];
        __syncthreads();
        red[tid] = ss;
        __syncthreads();
        for (int off = 128; off > 0; off >>= 1) {
            if (tid < off) red[tid] += red[tid + off];
            __syncthreads();
        }
        if (tid == 0) {
            const double rb = red[0] / (double)S_;
            acc += rb * rb;
        }
        __syncthreads();
    }
    if (tid == 0) meand[0] = acc / (double)B_;
}

// Per row s (one b): softmax over all 4 heads (fp32), float4-vectorized I/O.
__global__ __launch_bounds__(256) void softmax_fused(
    const float* __restrict__ scores, bf16* __restrict__ P, long p_h, int p_row,
    float* __restrict__ avgw, float* __restrict__ rowsum) {
    const int s = blockIdx.x, tid = threadIdx.x;
    __shared__ float red[256];
    float wacc[8] = {0, 0, 0, 0, 0, 0, 0, 0};
    for (int h = 0; h < H_; h++) {
        const float* rp = scores + ((size_t)h * S_ + s) * S_;
        bf16* pp = P + (size_t)h * p_h + (size_t)s * p_row;
        const float4 va = ((const float4*)rp)[tid];
        const float4 vb = ((const float4*)rp)[256 + tid];
        float v[8] = {va.x, va.y, va.z, va.w, vb.x, vb.y, vb.z, vb.w};
        float m = -1e30f;
#pragma unroll
        for (int i = 0; i < 8; i++) m = fmaxf(m, v[i]);
        red[tid] = m;
        __syncthreads();
        for (int off = 128; off > 0; off >>= 1) {
            if (tid < off) red[tid] = fmaxf(red[tid], red[tid + off]);
            __syncthreads();
        }
        m = red[0];
        __syncthreads();
        float sum = 0.0f;
#pragma unroll
        for (int i = 0; i < 8; i++) {
            v[i] = expf(v[i] - m);
            sum += v[i];
        }
        red[tid] = sum;
        __syncthreads();
        for (int off = 128; off > 0; off >>= 1) {
            if (tid < off) red[tid] += red[tid + off];
            __syncthreads();
        }
        const float inv = 1.0f / red[0];
        __syncthreads();
        s16x4 pk0, pk1;
#pragma unroll
        for (int j = 0; j < 4; j++) {
            const float w0 = v[j] * inv;
            const float w1 = v[4 + j] * inv;
            pk0[j] = bfb(w0);
            pk1[j] = bfb(w1);
            wacc[j] += w0;
            wacc[4 + j] += w1;
        }
        *(s16x4*)(pp + (size_t)tid * 4) = pk0;
        *(s16x4*)(pp + 1024 + (size_t)tid * 4) = pk1;
    }
    float4 a0, a1;
    a0.x = wacc[0] * 0.25f; a0.y = wacc[1] * 0.25f;
    a0.z = wacc[2] * 0.25f; a0.w = wacc[3] * 0.25f;
    a1.x = wacc[4] * 0.25f; a1.y = wacc[5] * 0.25f;
    a1.z = wacc[6] * 0.25f; a1.w = wacc[7] * 0.25f;
    float* ar = avgw + (size_t)s * S_;
    ((float4*)ar)[tid] = a0;
    ((float4*)ar)[256 + tid] = a1;
    const float asum = a0.x + a0.y + a0.z + a0.w + a1.x + a1.y + a1.z + a1.w;
    red[tid] = asum;
    __syncthreads();
    for (int off = 128; off > 0; off >>= 1) {
        if (tid < off) red[tid] += red[tid + off];
        __syncthreads();
    }
    if (tid == 0) rowsum[s] = red[0];
}

// y = proj + Wo_b + emb; LayerNorm(y) in place (float4-vectorized)
__global__ __launch_bounds__(256) void ln_kernel(float* __restrict__ out,
                                                 const float* __restrict__ emb,
                                                 const float* __restrict__ wob,
                                                 const float* __restrict__ g,
                                                 const float* __restrict__ beta) {
    const long row = blockIdx.x;
    float* o = out + row * D_;
    const float* e = emb + row * D_;
    const int tid = threadIdx.x;
    __shared__ float red[256];
    const float4 vo = ((const float4*)o)[tid];
    const float4 vw = ((const float4*)wob)[tid];
    const float4 ve = ((const float4*)e)[tid];
    float v[4] = {vo.x + vw.x + ve.x, vo.y + vw.y + ve.y,
                  vo.z + vw.z + ve.z, vo.w + vw.w + ve.w};
    red[tid] = v[0] + v[1] + v[2] + v[3];
    __syncthreads();
    for (int off = 128; off > 0; off >>= 1) {
        if (tid < off) red[tid] += red[tid + off];
        __syncthreads();
    }
    const float mu = red[0] * (1.0f / 1024.0f);
    __syncthreads();
    float vs = 0.0f;
#pragma unroll
    for (int i = 0; i < 4; i++) {
        const float d = v[i] - mu;
        vs += d * d;
    }
    red[tid] = vs;
    __syncthreads();
    for (int off = 128; off > 0; off >>= 1) {
        if (tid < off) red[tid] += red[tid + off];
        __syncthreads();
    }
    const float var = red[0] * (1.0f / 1024.0f);
    const float inv = 1.0f / sqrtf(var + 1e-5f);
    const float4 g4 = ((const float4*)g)[tid];
    const float4 b4 = ((const float4*)beta)[tid];
    float4 r4;
    r4.x = (v[0] - mu) * inv * g4.x + b4.x;
    r4.y = (v[1] - mu) * inv * g4.y + b4.y;
    r4.z = (v[2] - mu) * inv * g4.z + b4.z;
    r4.w = (v[3] - mu) * inv * g4.w + b4.w;
    ((float4*)o)[tid] = r4;
}

__global__ __launch_bounds__(256) void guilt_kernel(const float* __restrict__ rowsum,
                                                    float* __restrict__ guilt) {
    const int b = blockIdx.x, tid = threadIdx.x;
    const float* r = rowsum + (long)b * S_;
    float* gq = guilt + (long)b * S_;
    __shared__ float red[256];
    float v[8];
    float m = -1e30f;
#pragma unroll
    for (int i = 0; i < 8; i++) {
        v[i] = r[tid + 256 * i];
        m = fmaxf(m, v[i]);
    }
    red[tid] = m;
    __syncthreads();
    for (int off = 128; off > 0; off >>= 1) {
        if (tid < off) red[tid] = fmaxf(red[tid], red[tid + off]);
        __syncthreads();
    }
    m = red[0];
    __syncthreads();
    float sum = 0.0f;
#pragma unroll
    for (int i = 0; i < 8; i++) {
        v[i] = expf(v[i] - m);
        sum += v[i];
    }
    red[tid] = sum;
    __syncthreads();
    for (int off = 128; off > 0; off >>= 1) {
        if (tid < off) red[tid] += red[tid + off];
        __syncthreads();
    }
    const float inv = 1.0f / red[0];
#pragma unroll
    for (int i = 0; i < 8; i++) gq[tid + 256 * i] = v[i] * inv;
}

extern "C" void kernel_launch(void* const* d_in, const int* in_sizes, int n_in,
                              void* d_out, int out_size, void* d_ws, size_t ws_size,
                              hipStream_t stream) {
    const float* emb = (const float*)d_in[0];
    const float* Wq = (const float*)d_in[1];
    const float* Wk = (const float*)d_in[2];
    const float* Wv = (const float*)d_in[3];
    const float* bias_sc = (const float*)d_in[4];
    const float* Wo_w = (const float*)d_in[5];
    const float* Wo_b = (const float*)d_in[6];
    const float* ln_g = (const float*)d_in[7];
    const float* ln_bt = (const float*)d_in[8];

    char* ws = (char*)d_ws;
    size_t off = 0;
    auto alloc = [&](size_t bytes) {
        size_t o = off;
        off = (off + bytes + 255) & ~(size_t)255;
        return o;
    };
    bf16* embb = (bf16*)(ws + alloc((size_t)B_ * S_ * D_ * 2));
    bf16* concat = embb;  // alias: embb dead after QKV GEMMs, concat written later
    bf16* Qm = (bf16*)(ws + alloc((size_t)H_ * B_ * S_ * HD_ * 2));  // [H,B*S,hd]
    bf16* Km = (bf16*)(ws + alloc((size_t)H_ * B_ * S_ * HD_ * 2));
    bf16* Vtb = (bf16*)(ws + alloc((size_t)H_ * B_ * HD_ * S_ * 2)); // [H,B,hd,S]
    bf16* Wqb = (bf16*)(ws + alloc((size_t)H_ * HD_ * HD_ * 2));
    bf16* Wkb = (bf16*)(ws + alloc((size_t)H_ * HD_ * HD_ * 2));
    bf16* Wvb = (bf16*)(ws + alloc((size_t)H_ * HD_ * HD_ * 2));
    bf16* Wob = (bf16*)(ws + alloc((size_t)D_ * D_ * 2));
    double* mag1d = (double*)(ws + alloc((size_t)B_ * S_ * 8));
    double* v3d = (double*)(ws + alloc((size_t)B_ * S_ * 8));
    double* meand = (double*)(ws + alloc(256));
    float* rowsum = (float*)(ws + alloc((size_t)B_ * S_ * 4));
    float* scores = (float*)(ws + alloc((size_t)H_ * S_ * S_ * 4));  // one b
    bf16* Vraw = (bf16*)scores;  // alias: Vraw consumed (transposed) before scores b=0
    bf16* P = (bf16*)(ws + off);  // Path A only: [B,H,S,S] bf16
    const size_t need_batched = off + (size_t)B_ * H_ * S_ * S_ * 2;
    const bool batched = ws_size >= need_batched;

    float* outp = (float*)d_out;
    float* avgw = outp + (size_t)B_ * S_ * D_;
    float* guilt = avgw + (size_t)B_ * S_ * S_;

    // casts (Q-scale 1/16 folded into Wq)
    cvt_bf16<<<(B_ * S_ * D_) / 1024, 256, 0, stream>>>(emb, embb, B_ * S_ * D_, 1.0f);
    cvt_bf16<<<(H_ * HD_ * HD_) / 1024, 256, 0, stream>>>(Wq, Wqb, H_ * HD_ * HD_, 0.0625f);
    cvt_bf16<<<(H_ * HD_ * HD_) / 1024, 256, 0, stream>>>(Wk, Wkb, H_ * HD_ * HD_, 1.0f);
    cvt_bf16<<<(H_ * HD_ * HD_) / 1024, 256, 0, stream>>>(Wv, Wvb, H_ * HD_ * HD_, 1.0f);
    cvt_bf16<<<(D_ * D_) / 1024, 256, 0, stream>>>(Wo_w, Wob, D_ * D_, 1.0f);

    prep_kernel<<<B_ * S_, 256, 0, stream>>>(emb, mag1d, v3d);
    mean_kernel<<<1, 256, 0, stream>>>(mag1d, meand);

    // QKV projections: MFMA, M = B*S (=8192), N = hd, K = hd, z = head
    {
        const dim3 g(HD_ / 128, (B_ * S_) / 128, H_);
        const long sQ = (long)B_ * S_ * HD_;
        mfma_nt<1><<<g, 256, 0, stream>>>(HD_, embb, D_, 0, HD_,
                                          Wqb, HD_, 0, (long)HD_ * HD_,
                                          Qm, HD_, 0, sQ, H_, 0,
                                          nullptr, nullptr, nullptr, nullptr);
        mfma_nt<1><<<g, 256, 0, stream>>>(HD_, embb, D_, 0, HD_,
                                          Wkb, HD_, 0, (long)HD_ * HD_,
                                          Km, HD_, 0, sQ, H_, 0,
                                          nullptr, nullptr, nullptr, nullptr);
        mfma_nt<1><<<g, 256, 0, stream>>>(HD_, embb, D_, 0, HD_,
                                          Wvb, HD_, 0, (long)HD_ * HD_,
                                          Vraw, HD_, 0, sQ, H_, 0,
                                          nullptr, nullptr, nullptr, nullptr);
    }
    transpose_v<<<dim3(HD_ / 64, S_ / 64, H_ * B_), 256, 0, stream>>>(Vraw, Vtb);

    for (int b = 0; b < B_; b++) {
        // scores[h,s,t] = Q.K^T + bias  (fp32 out, per-b buffer stays L3-warm)
        mfma_nt<3><<<dim3(S_ / 128, S_ / 128, H_), 256, 0, stream>>>(
            HD_,
            Qm + (size_t)b * S_ * HD_, HD_, 0, (long)B_ * S_ * HD_,
            Km + (size_t)b * S_ * HD_, HD_, 0, (long)B_ * S_ * HD_,
            scores, S_, 0, (long)S_ * S_,
            H_, b, mag1d, v3d, meand, bias_sc);
        if (batched) {
            softmax_fused<<<S_, 256, 0, stream>>>(
                scores, P + (size_t)b * H_ * S_ * S_, (long)S_ * S_, S_,
                avgw + (size_t)b * S_ * S_, rowsum + (size_t)b * S_);
        } else {
            // P bf16 in place over the fp32 scores rows (row stride 2S)
            softmax_fused<<<S_, 256, 0, stream>>>(
                scores, (bf16*)scores, 2L * S_ * S_, 2 * S_,
                avgw + (size_t)b * S_ * S_, rowsum + (size_t)b * S_);
            mfma_nt<1><<<dim3(HD_ / 128, S_ / 128, H_), 256, 0, stream>>>(
                S_,
                (const bf16*)scores, 2 * S_, 0, 2L * S_ * S_,
                Vtb + (size_t)b * HD_ * S_, S_, 0, (long)B_ * HD_ * S_,
                concat + (size_t)b * S_ * D_, D_, 0, HD_,
                H_, 0, nullptr, nullptr, nullptr, nullptr);
        }
    }
    if (batched) {
        // attended = P.V for all (b,h): deep-pipelined counted-vmcnt kernel
        mfma_pv<<<256, 512, 0, stream>>>(P, Vtb, concat);
    }

    // out = concat @ Wo^T (MFMA, bf16 Wo)
    mfma_nt<0><<<dim3(D_ / 128, (B_ * S_) / 128, 1), 256, 0, stream>>>(
        D_, concat, D_, 0, 0, Wob, D_, 0, 0, outp, D_, 0, 0,
        1, 0, nullptr, nullptr, nullptr, nullptr);

    ln_kernel<<<B_ * S_, 256, 0, stream>>>(outp, emb, Wo_b, ln_g, ln_bt);
    guilt_kernel<<<B_, 256, 0, stream>>>(rowsum, guilt);
}

// Round 8
// 504.204 us; speedup vs baseline: 1.9403x; 1.0119x over previous
//
#include <hip/hip_runtime.h>
#include <hip/hip_bf16.h>
#include <math.h>

#define S_ 2048
#define D_ 1024
#define H_ 4
#define HD_ 256
#define B_ 4

typedef __hip_bfloat16 bf16;
typedef short s16x8 __attribute__((ext_vector_type(8)));
typedef short s16x4 __attribute__((ext_vector_type(4)));
typedef float f32x4 __attribute__((ext_vector_type(4)));

// async global->LDS, 16B per lane; LDS dest is wave-uniform base + lane*16
#define GLOAD16(g, l)                                             \
    __builtin_amdgcn_global_load_lds(                             \
        (const __attribute__((address_space(1))) void*)(g),       \
        (__attribute__((address_space(3))) void*)(l), 16, 0, 0)

// counted-vmcnt wait + raw barrier (does NOT drain vmcnt) + scheduling fence
#define WAITB(N)                                              \
    asm volatile("s_waitcnt vmcnt(" #N ")" ::: "memory");     \
    __builtin_amdgcn_s_barrier();                             \
    __builtin_amdgcn_sched_barrier(0);

static __device__ inline short bfb(float x) {
    bf16 t = __float2bfloat16(x);
    short s;
    __builtin_memcpy(&s, &t, 2);
    return s;
}

// ---------------------------------------------------------------------------
// MFMA NT GEMM: C[m,n] = sum_k A[m,k]*B[n,k], A/B bf16 row-major.
// 128x128 tile, BK=32, 256 threads = 4 waves (2x2), each wave 4x4 frags of
// 16x16x32 bf16 MFMA. Counted-vmcnt pipeline: 3 LDS buffer pairs, depth-2
// prefetch, vmcnt(4) + raw barrier per step (R7, measured neutral, kept).
// MODE: 0 = fp32 store, 1 = bf16 store, 3 = fp32 store + legal-bias.
// R8: h==2 proximity bias reads a precomputed table (bit-identical values).
// ---------------------------------------------------------------------------
template <int MODE>
__global__ __launch_bounds__(256) void mfma_nt(
    int K,
    const bf16* __restrict__ A, int lda, long sA_b, long sA_h,
    const bf16* __restrict__ Bm, int ldb, long sB_b, long sB_h,
    void* __restrict__ Cp, int ldc, long sC_b, long sC_h,
    int zdiv, int bbase,
    const double* __restrict__ mag1d, const double* __restrict__ v3d,
    const double* __restrict__ meand, const float* __restrict__ bias_sc,
    const float* __restrict__ proxt)
{
    __shared__ __align__(16) short As[3][128 * 32];
    __shared__ __align__(16) short Bs[3][128 * 32];

    const int tid = threadIdx.x;
    const int w = tid >> 6, lane = tid & 63;
    const int srow = lane >> 2;                          // staging: 16 rows/inst
    const int scol = (((lane & 3) ^ (srow & 3)) << 3);   // pre-swizzled source col
    const int quad = lane >> 4, r = lane & 15;           // mfma fragment coords
    const int qx = quad ^ (r & 3);                       // swizzled read slot
    const int wr = (w >> 1) * 64, wc = (w & 1) * 64;     // wave's 64x64 quadrant
    const int zb = blockIdx.z / zdiv, zh = blockIdx.z % zdiv;

    const bf16* Ap = A + (size_t)zb * sA_b + (size_t)zh * sA_h +
                     (size_t)blockIdx.y * 128 * lda;
    const bf16* Bp = Bm + (size_t)zb * sB_b + (size_t)zh * sB_h +
                     (size_t)blockIdx.x * 128 * ldb;

    f32x4 acc[4][4] = {};

    auto stage = [&](int bs, int k0) {
#pragma unroll
        for (int l = 0; l < 2; l++) {
            GLOAD16(Ap + (size_t)(w * 32 + l * 16 + srow) * lda + (k0 + scol),
                    &As[bs][(w * 32 + l * 16) * 32]);
            GLOAD16(Bp + (size_t)(w * 32 + l * 16 + srow) * ldb + (k0 + scol),
                    &Bs[bs][(w * 32 + l * 16) * 32]);
        }
    };
    auto compute = [&](int bs) {
        const s16x8* A8 = (const s16x8*)&As[bs][0];
        const s16x8* B8 = (const s16x8*)&Bs[bs][0];
        s16x8 af[4], bfv[4];
#pragma unroll
        for (int i = 0; i < 4; i++) af[i] = A8[(wr + i * 16 + r) * 4 + qx];
#pragma unroll
        for (int j = 0; j < 4; j++) bfv[j] = B8[(wc + j * 16 + r) * 4 + qx];
        __builtin_amdgcn_s_setprio(1);
#pragma unroll
        for (int i = 0; i < 4; i++)
#pragma unroll
            for (int j = 0; j < 4; j++)
                acc[i][j] = __builtin_amdgcn_mfma_f32_16x16x32_bf16(
                    af[i], bfv[j], acc[i][j], 0, 0, 0);
        __builtin_amdgcn_s_setprio(0);
    };

    const int NT = K >> 5;
    stage(0, 0);
    stage(1, 32);
    int cb = 0;
#pragma unroll 1
    for (int t = 0; t < NT - 2; ++t) {
        WAITB(4);
        int sb = cb + 2; if (sb >= 3) sb -= 3;
        stage(sb, (t + 2) * 32);
        compute(cb);
        cb = (cb == 2) ? 0 : cb + 1;
    }
    WAITB(4);
    compute(cb);
    cb = (cb == 2) ? 0 : cb + 1;
    WAITB(0);
    compute(cb);

    // C/D layout: col = lane&15, row = quad*4 + reg   [m89-verified]
    const int row0 = blockIdx.y * 128 + wr + quad * 4;
    const int col0 = blockIdx.x * 128 + wc + r;

    if (MODE == 0) {
        float* C = (float*)Cp + (size_t)zb * sC_b + (size_t)zh * sC_h;
#pragma unroll
        for (int i = 0; i < 4; i++)
#pragma unroll
            for (int j = 0; j < 4; j++)
#pragma unroll
                for (int p = 0; p < 4; p++)
                    C[(size_t)(row0 + i * 16 + p) * ldc + (col0 + j * 16)] = acc[i][j][p];
    } else if (MODE == 1) {
        bf16* C = (bf16*)Cp + (size_t)zb * sC_b + (size_t)zh * sC_h;
#pragma unroll
        for (int i = 0; i < 4; i++)
#pragma unroll
            for (int j = 0; j < 4; j++)
#pragma unroll
                for (int p = 0; p < 4; p++)
                    C[(size_t)(row0 + i * 16 + p) * ldc + (col0 + j * 16)] =
                        __float2bfloat16(acc[i][j][p]);
    } else {  // MODE 3: scores + legal bias; h = zh, batch = bbase + zb
        float* C = (float*)Cp + (size_t)zb * sC_b + (size_t)zh * sC_h;
        const int h = zh;
        const int bbatch = bbase + zb;
        const float bsc = bias_sc[h];
        if (h == 0) {  // causal triu(k=1)
#pragma unroll
            for (int i = 0; i < 4; i++)
#pragma unroll
                for (int j = 0; j < 4; j++)
#pragma unroll
                    for (int p = 0; p < 4; p++) {
                        const int rr = row0 + i * 16 + p, c = col0 + j * 16;
                        C[(size_t)rr * ldc + c] = acc[i][j][p] + ((c > rr) ? bsc : 0.0f);
                    }
        } else if (h == 2) {  // proximity: table lookup, bit-identical to expf
#pragma unroll
            for (int i = 0; i < 4; i++)
#pragma unroll
                for (int j = 0; j < 4; j++)
#pragma unroll
                    for (int p = 0; p < 4; p++) {
                        const int rr = row0 + i * 16 + p, c = col0 + j * 16;
                        int d = c - rr; d = d < 0 ? -d : d;
                        C[(size_t)rr * ldc + c] = acc[i][j][p] + bsc * proxt[d];
                    }
        } else {  // h==1 intent (> mean) / h==3 violation (> 0.5), exact fp64 compare
            const double* src = (h == 1) ? mag1d : v3d;
            const double thr = (h == 1) ? meand[0] : 0.5;
            double rv[16], cv[4];
#pragma unroll
            for (int i = 0; i < 4; i++)
#pragma unroll
                for (int p = 0; p < 4; p++)
                    rv[i * 4 + p] = src[(size_t)bbatch * S_ + row0 + i * 16 + p];
#pragma unroll
            for (int j = 0; j < 4; j++)
                cv[j] = src[(size_t)bbatch * S_ + col0 + j * 16];
#pragma unroll
            for (int i = 0; i < 4; i++)
#pragma unroll
                for (int j = 0; j < 4; j++)
#pragma unroll
                    for (int p = 0; p < 4; p++) {
                        const int rr = row0 + i * 16 + p, c = col0 + j * 16;
                        C[(size_t)rr * ldc + c] =
                            acc[i][j][p] + ((rv[i * 4 + p] * cv[j] > thr) ? bsc : 0.0f);
                    }
        }
    }
}

// ---------------------------------------------------------------------------
// Dedicated batched P.V GEMM (R2 verified ~69us version):
// Tile 128x256, 512 threads = 8 waves. 6 LDS buffers, prefetch depth 5,
// vmcnt(12) + raw barrier per step; epilogue drains 12->9->6->3->0.
// XCD-clustered (b,h) mapping keeps V panels L2-hot.
// ---------------------------------------------------------------------------
__global__ __launch_bounds__(512) void mfma_pv(const bf16* __restrict__ Pm,
                                               const bf16* __restrict__ Vt,
                                               bf16* __restrict__ Cc) {
    __shared__ __align__(16) short L[6][12288];

    const int tid = threadIdx.x;
    const int w = tid >> 6, lane = tid & 63;
    const int quad = lane >> 4, r = lane & 15;
    const int qx = quad ^ (r & 3);                    // swizzled read slot
    const int wr = (w >> 2) * 64, wc = (w & 3) * 64;  // wave's 64x64 subtile

    const int bid = blockIdx.x;
    const int bh = (bid & 7) * 2 + ((bid >> 3) >> 4);  // 0..15, bijective
    const int rb = (bid >> 3) & 15;                    // row-block 0..15
    const int b = bh >> 2, h = bh & 3;

    const bf16* Ap = Pm + ((size_t)bh * S_ + (size_t)rb * 128) * S_;  // P rows
    const bf16* Bp = Vt + (size_t)(h * B_ + b) * HD_ * S_;            // V^T panel

    const int srow = tid >> 2;                          // 0..127
    const int scol = (((tid & 3) ^ (srow & 3)) << 3);   // pre-swizzled source col
    const int wbase = w * 512;                          // wave's 16-row LDS slab

    f32x4 acc[4][4] = {};

    auto stage = [&](int bs, int t) {
        short* sb = &L[bs][0];
        const int k0 = t * 32;
        GLOAD16(Ap + (size_t)srow * S_ + (k0 + scol), sb + wbase);
        GLOAD16(Bp + (size_t)srow * S_ + (k0 + scol), sb + 4096 + wbase);
        GLOAD16(Bp + (size_t)(128 + srow) * S_ + (k0 + scol), sb + 8192 + wbase);
    };
    auto compute = [&](int bs) {
        const s16x8* A8 = (const s16x8*)&L[bs][0];
        const s16x8* B8 = (const s16x8*)&L[bs][4096];
        s16x8 af[4], bfv[4];
#pragma unroll
        for (int i = 0; i < 4; i++) af[i] = A8[(wr + i * 16 + r) * 4 + qx];
#pragma unroll
        for (int j = 0; j < 4; j++) bfv[j] = B8[(wc + j * 16 + r) * 4 + qx];
        __builtin_amdgcn_s_setprio(1);
#pragma unroll
        for (int i = 0; i < 4; i++)
#pragma unroll
            for (int j = 0; j < 4; j++)
                acc[i][j] = __builtin_amdgcn_mfma_f32_16x16x32_bf16(
                    af[i], bfv[j], acc[i][j], 0, 0, 0);
        __builtin_amdgcn_s_setprio(0);
    };

    stage(0, 0); stage(1, 1); stage(2, 2); stage(3, 3); stage(4, 4);

    int cb = 0, sn = 5;  // compute / stage buffer indices (mod 6)
#pragma unroll 1
    for (int t = 0; t < 59; ++t) {  // NT=64; stages t+5 = 5..63
        WAITB(12);
        stage(sn, t + 5);
        compute(cb);
        cb = (cb == 5) ? 0 : cb + 1;
        sn = (sn == 5) ? 0 : sn + 1;
    }
    WAITB(12); compute(cb); cb = (cb == 5) ? 0 : cb + 1;
    WAITB(9);  compute(cb); cb = (cb == 5) ? 0 : cb + 1;
    WAITB(6);  compute(cb); cb = (cb == 5) ? 0 : cb + 1;
    WAITB(3);  compute(cb); cb = (cb == 5) ? 0 : cb + 1;
    WAITB(0);  compute(cb);

    const int row0 = rb * 128 + wr + quad * 4;
    const int col0 = h * HD_ + wc + r;
    bf16* C = Cc + (size_t)b * S_ * D_;
#pragma unroll
    for (int i = 0; i < 4; i++)
#pragma unroll
        for (int j = 0; j < 4; j++)
#pragma unroll
            for (int p = 0; p < 4; p++)
                C[(size_t)(row0 + i * 16 + p) * D_ + col0 + j * 16] =
                    __float2bfloat16(acc[i][j][p]);
}

// fp32 -> bf16 (optionally scaled), 4 elems/thread
__global__ __launch_bounds__(256) void cvt_bf16(const float* __restrict__ in,
                                                bf16* __restrict__ out, int n,
                                                float scale) {
    const size_t i0 = ((size_t)blockIdx.x * 256 + threadIdx.x) * 4;
    if (i0 + 3 < (size_t)n) {
        const float4 v = *(const float4*)(in + i0);
        out[i0 + 0] = __float2bfloat16(v.x * scale);
        out[i0 + 1] = __float2bfloat16(v.y * scale);
        out[i0 + 2] = __float2bfloat16(v.z * scale);
        out[i0 + 3] = __float2bfloat16(v.w * scale);
    }
}

// proximity bias table: proxt[d] = expf(-d/2048), d in [0, S) -- the exact
// expression the h==2 epilogue used, so results are bit-identical.
__global__ __launch_bounds__(256) void prox_kernel(float* __restrict__ proxt) {
    const int i = blockIdx.x * 256 + threadIdx.x;
    if (i < S_) proxt[i] = expf(-(float)i * (1.0f / 2048.0f));
}

// Vraw [H, B*S, hd] -> Vt [H, B, hd, S]  (64x64 bf16 LDS tile transpose)
__global__ __launch_bounds__(256) void transpose_v(const bf16* __restrict__ in,
                                                   bf16* __restrict__ out) {
    const int h = blockIdx.z / B_, b = blockIdx.z % B_;
    const int e0 = blockIdx.x * 64, s0 = blockIdx.y * 64;
    __shared__ short t[64][66];
    const int tid = threadIdx.x;
    const int rr = tid >> 2;            // 0..63
    const int cc = (tid & 3) << 4;      // 0,16,32,48
    const bf16* ip = in + (((size_t)h * B_ * S_) + (size_t)b * S_ + s0) * HD_ + e0;
    const s16x8 v0 = *(const s16x8*)(ip + (size_t)rr * HD_ + cc);
    const s16x8 v1 = *(const s16x8*)(ip + (size_t)rr * HD_ + cc + 8);
#pragma unroll
    for (int i = 0; i < 8; i++) {
        t[rr][cc + i] = v0[i];
        t[rr][cc + 8 + i] = v1[i];
    }
    __syncthreads();
    bf16* op = out + (((size_t)h * B_ + b) * HD_ + e0 + rr) * S_ + s0 + cc;
    s16x8 o0, o1;
#pragma unroll
    for (int i = 0; i < 8; i++) {
        o0[i] = t[cc + i][rr];
        o1[i] = t[cc + 8 + i][rr];
    }
    *(s16x8*)op = o0;
    *(s16x8*)(op + 8) = o1;
}

// mag1[b,s] = ||emb[b,s,256:512]|| (fp64), v3[b,s] = emb[b,s,1023]
__global__ __launch_bounds__(256) void prep_kernel(const float* __restrict__ emb,
                                                   double* __restrict__ mag1d,
                                                   double* __restrict__ v3d) {
    const long row = blockIdx.x;
    const int tid = threadIdx.x;
    const float x = emb[row * D_ + 256 + tid];
    __shared__ double red[256];
    red[tid] = (double)x * (double)x;
    __syncthreads();
    for (int off = 128; off > 0; off >>= 1) {
        if (tid < off) red[tid] += red[tid + off];
        __syncthreads();
    }
    if (tid == 0) {
        mag1d[row] = sqrt(red[0]);
        v3d[row] = (double)emb[row * D_ + 1023];
    }
}

__global__ __launch_bounds__(256) void mean_kernel(const double* __restrict__ mag1d,
                                                   double* __restrict__ meand) {
    const int tid = threadIdx.x;
    __shared__ double red[256];
    double acc = 0.0;
    for (int b = 0; b < B_; b++) {
        double ss = 0.0;
        for (int i = tid; i < S_; i += 256) ss += mag1d[(long)b * S_ + i];
        __syncthreads();
        red[tid] = ss;
        __syncthreads();
        for (int off = 128; off > 0; off >>= 1) {
            if (tid < off) red[tid] += red[tid + off];
            __syncthreads();
        }
        if (tid == 0) {
            const double rb = red[0] / (double)S_;
            acc += rb * rb;
        }
        __syncthreads();
    }
    if (tid == 0) meand[0] = acc / (double)B_;
}

// Per row s (one b): softmax over all 4 heads (fp32), float4-vectorized I/O.
// R8: wave-level __shfl_xor butterfly reductions (4 barriers/head instead of
// ~16) and __expf (hw v_exp_f32) instead of libm expf.
__global__ __launch_bounds__(256) void softmax_fused(
    const float* __restrict__ scores, bf16* __restrict__ P, long p_h, int p_row,
    float* __restrict__ avgw, float* __restrict__ rowsum) {
    const int s = blockIdx.x, tid = threadIdx.x;
    const int wv = tid >> 6, lane = tid & 63;
    __shared__ float red[4];
    float wacc[8] = {0, 0, 0, 0, 0, 0, 0, 0};
    for (int h = 0; h < H_; h++) {
        const float* rp = scores + ((size_t)h * S_ + s) * S_;
        bf16* pp = P + (size_t)h * p_h + (size_t)s * p_row;
        const float4 va = ((const float4*)rp)[tid];
        const float4 vb = ((const float4*)rp)[256 + tid];
        float v[8] = {va.x, va.y, va.z, va.w, vb.x, vb.y, vb.z, vb.w};
        float m = -1e30f;
#pragma unroll
        for (int i = 0; i < 8; i++) m = fmaxf(m, v[i]);
#pragma unroll
        for (int d = 32; d; d >>= 1) m = fmaxf(m, __shfl_xor(m, d));
        if (lane == 0) red[wv] = m;
        __syncthreads();
        m = fmaxf(fmaxf(red[0], red[1]), fmaxf(red[2], red[3]));
        __syncthreads();
        float sum = 0.0f;
#pragma unroll
        for (int i = 0; i < 8; i++) {
            v[i] = __expf(v[i] - m);
            sum += v[i];
        }
#pragma unroll
        for (int d = 32; d; d >>= 1) sum += __shfl_xor(sum, d);
        if (lane == 0) red[wv] = sum;
        __syncthreads();
        const float inv = 1.0f / (red[0] + red[1] + red[2] + red[3]);
        __syncthreads();
        s16x4 pk0, pk1;
#pragma unroll
        for (int j = 0; j < 4; j++) {
            const float w0 = v[j] * inv;
            const float w1 = v[4 + j] * inv;
            pk0[j] = bfb(w0);
            pk1[j] = bfb(w1);
            wacc[j] += w0;
            wacc[4 + j] += w1;
        }
        *(s16x4*)(pp + (size_t)tid * 4) = pk0;
        *(s16x4*)(pp + 1024 + (size_t)tid * 4) = pk1;
    }
    float4 a0, a1;
    a0.x = wacc[0] * 0.25f; a0.y = wacc[1] * 0.25f;
    a0.z = wacc[2] * 0.25f; a0.w = wacc[3] * 0.25f;
    a1.x = wacc[4] * 0.25f; a1.y = wacc[5] * 0.25f;
    a1.z = wacc[6] * 0.25f; a1.w = wacc[7] * 0.25f;
    float* ar = avgw + (size_t)s * S_;
    ((float4*)ar)[tid] = a0;
    ((float4*)ar)[256 + tid] = a1;
    float asum = a0.x + a0.y + a0.z + a0.w + a1.x + a1.y + a1.z + a1.w;
#pragma unroll
    for (int d = 32; d; d >>= 1) asum += __shfl_xor(asum, d);
    if (lane == 0) red[wv] = asum;
    __syncthreads();
    if (tid == 0) rowsum[s] = red[0] + red[1] + red[2] + red[3];
}

// y = proj + Wo_b + emb; LayerNorm(y) in place (float4-vectorized)
__global__ __launch_bounds__(256) void ln_kernel(float* __restrict__ out,
                                                 const float* __restrict__ emb,
                                                 const float* __restrict__ wob,
                                                 const float* __restrict__ g,
                                                 const float* __restrict__ beta) {
    const long row = blockIdx.x;
    float* o = out + row * D_;
    const float* e = emb + row * D_;
    const int tid = threadIdx.x;
    __shared__ float red[256];
    const float4 vo = ((const float4*)o)[tid];
    const float4 vw = ((const float4*)wob)[tid];
    const float4 ve = ((const float4*)e)[tid];
    float v[4] = {vo.x + vw.x + ve.x, vo.y + vw.y + ve.y,
                  vo.z + vw.z + ve.z, vo.w + vw.w + ve.w};
    red[tid] = v[0] + v[1] + v[2] + v[3];
    __syncthreads();
    for (int off = 128; off > 0; off >>= 1) {
        if (tid < off) red[tid] += red[tid + off];
        __syncthreads();
    }
    const float mu = red[0] * (1.0f / 1024.0f);
    __syncthreads();
    float vs = 0.0f;
#pragma unroll
    for (int i = 0; i < 4; i++) {
        const float d = v[i] - mu;
        vs += d * d;
    }
    red[tid] = vs;
    __syncthreads();
    for (int off = 128; off > 0; off >>= 1) {
        if (tid < off) red[tid] += red[tid + off];
        __syncthreads();
    }
    const float var = red[0] * (1.0f / 1024.0f);
    const float inv = 1.0f / sqrtf(var + 1e-5f);
    const float4 g4 = ((const float4*)g)[tid];
    const float4 b4 = ((const float4*)beta)[tid];
    float4 r4;
    r4.x = (v[0] - mu) * inv * g4.x + b4.x;
    r4.y = (v[1] - mu) * inv * g4.y + b4.y;
    r4.z = (v[2] - mu) * inv * g4.z + b4.z;
    r4.w = (v[3] - mu) * inv * g4.w + b4.w;
    ((float4*)o)[tid] = r4;
}

__global__ __launch_bounds__(256) void guilt_kernel(const float* __restrict__ rowsum,
                                                    float* __restrict__ guilt) {
    const int b = blockIdx.x, tid = threadIdx.x;
    const float* r = rowsum + (long)b * S_;
    float* gq = guilt + (long)b * S_;
    __shared__ float red[256];
    float v[8];
    float m = -1e30f;
#pragma unroll
    for (int i = 0; i < 8; i++) {
        v[i] = r[tid + 256 * i];
        m = fmaxf(m, v[i]);
    }
    red[tid] = m;
    __syncthreads();
    for (int off = 128; off > 0; off >>= 1) {
        if (tid < off) red[tid] = fmaxf(red[tid], red[tid + off]);
        __syncthreads();
    }
    m = red[0];
    __syncthreads();
    float sum = 0.0f;
#pragma unroll
    for (int i = 0; i < 8; i++) {
        v[i] = expf(v[i] - m);
        sum += v[i];
    }
    red[tid] = sum;
    __syncthreads();
    for (int off = 128; off > 0; off >>= 1) {
        if (tid < off) red[tid] += red[tid + off];
        __syncthreads();
    }
    const float inv = 1.0f / red[0];
#pragma unroll
    for (int i = 0; i < 8; i++) gq[tid + 256 * i] = v[i] * inv;
}

extern "C" void kernel_launch(void* const* d_in, const int* in_sizes, int n_in,
                              void* d_out, int out_size, void* d_ws, size_t ws_size,
                              hipStream_t stream) {
    const float* emb = (const float*)d_in[0];
    const float* Wq = (const float*)d_in[1];
    const float* Wk = (const float*)d_in[2];
    const float* Wv = (const float*)d_in[3];
    const float* bias_sc = (const float*)d_in[4];
    const float* Wo_w = (const float*)d_in[5];
    const float* Wo_b = (const float*)d_in[6];
    const float* ln_g = (const float*)d_in[7];
    const float* ln_bt = (const float*)d_in[8];

    char* ws = (char*)d_ws;
    size_t off = 0;
    auto alloc = [&](size_t bytes) {
        size_t o = off;
        off = (off + bytes + 255) & ~(size_t)255;
        return o;
    };
    bf16* embb = (bf16*)(ws + alloc((size_t)B_ * S_ * D_ * 2));
    bf16* concat = embb;  // alias: embb dead after QKV GEMMs, concat written later
    bf16* Qm = (bf16*)(ws + alloc((size_t)H_ * B_ * S_ * HD_ * 2));  // [H,B*S,hd]
    bf16* Km = (bf16*)(ws + alloc((size_t)H_ * B_ * S_ * HD_ * 2));
    bf16* Vtb = (bf16*)(ws + alloc((size_t)H_ * B_ * HD_ * S_ * 2)); // [H,B,hd,S]
    bf16* Wqb = (bf16*)(ws + alloc((size_t)H_ * HD_ * HD_ * 2));
    bf16* Wkb = (bf16*)(ws + alloc((size_t)H_ * HD_ * HD_ * 2));
    bf16* Wvb = (bf16*)(ws + alloc((size_t)H_ * HD_ * HD_ * 2));
    bf16* Wob = (bf16*)(ws + alloc((size_t)D_ * D_ * 2));
    double* mag1d = (double*)(ws + alloc((size_t)B_ * S_ * 8));
    double* v3d = (double*)(ws + alloc((size_t)B_ * S_ * 8));
    double* meand = (double*)(ws + alloc(256));
    float* rowsum = (float*)(ws + alloc((size_t)B_ * S_ * 4));
    float* proxt = (float*)(ws + alloc((size_t)S_ * 4));
    float* scores = (float*)(ws + alloc((size_t)H_ * S_ * S_ * 4));  // one b
    bf16* Vraw = (bf16*)scores;  // alias: Vraw consumed (transposed) before scores b=0
    bf16* P = (bf16*)(ws + off);  // Path A only: [B,H,S,S] bf16
    const size_t need_batched = off + (size_t)B_ * H_ * S_ * S_ * 2;
    const bool batched = ws_size >= need_batched;

    float* outp = (float*)d_out;
    float* avgw = outp + (size_t)B_ * S_ * D_;
    float* guilt = avgw + (size_t)B_ * S_ * S_;

    // casts (Q-scale 1/16 folded into Wq)
    cvt_bf16<<<(B_ * S_ * D_) / 1024, 256, 0, stream>>>(emb, embb, B_ * S_ * D_, 1.0f);
    cvt_bf16<<<(H_ * HD_ * HD_) / 1024, 256, 0, stream>>>(Wq, Wqb, H_ * HD_ * HD_, 0.0625f);
    cvt_bf16<<<(H_ * HD_ * HD_) / 1024, 256, 0, stream>>>(Wk, Wkb, H_ * HD_ * HD_, 1.0f);
    cvt_bf16<<<(H_ * HD_ * HD_) / 1024, 256, 0, stream>>>(Wv, Wvb, H_ * HD_ * HD_, 1.0f);
    cvt_bf16<<<(D_ * D_) / 1024, 256, 0, stream>>>(Wo_w, Wob, D_ * D_, 1.0f);

    prep_kernel<<<B_ * S_, 256, 0, stream>>>(emb, mag1d, v3d);
    mean_kernel<<<1, 256, 0, stream>>>(mag1d, meand);
    prox_kernel<<<S_ / 256, 256, 0, stream>>>(proxt);

    // QKV projections: MFMA, M = B*S (=8192), N = hd, K = hd, z = head
    {
        const dim3 g(HD_ / 128, (B_ * S_) / 128, H_);
        const long sQ = (long)B_ * S_ * HD_;
        mfma_nt<1><<<g, 256, 0, stream>>>(HD_, embb, D_, 0, HD_,
                                          Wqb, HD_, 0, (long)HD_ * HD_,
                                          Qm, HD_, 0, sQ, H_, 0,
                                          nullptr, nullptr, nullptr, nullptr, nullptr);
        mfma_nt<1><<<g, 256, 0, stream>>>(HD_, embb, D_, 0, HD_,
                                          Wkb, HD_, 0, (long)HD_ * HD_,
                                          Km, HD_, 0, sQ, H_, 0,
                                          nullptr, nullptr, nullptr, nullptr, nullptr);
        mfma_nt<1><<<g, 256, 0, stream>>>(HD_, embb, D_, 0, HD_,
                                          Wvb, HD_, 0, (long)HD_ * HD_,
                                          Vraw, HD_, 0, sQ, H_, 0,
                                          nullptr, nullptr, nullptr, nullptr, nullptr);
    }
    transpose_v<<<dim3(HD_ / 64, S_ / 64, H_ * B_), 256, 0, stream>>>(Vraw, Vtb);

    for (int b = 0; b < B_; b++) {
        // scores[h,s,t] = Q.K^T + bias  (fp32 out, per-b buffer stays L3-warm)
        mfma_nt<3><<<dim3(S_ / 128, S_ / 128, H_), 256, 0, stream>>>(
            HD_,
            Qm + (size_t)b * S_ * HD_, HD_, 0, (long)B_ * S_ * HD_,
            Km + (size_t)b * S_ * HD_, HD_, 0, (long)B_ * S_ * HD_,
            scores, S_, 0, (long)S_ * S_,
            H_, b, mag1d, v3d, meand, bias_sc, proxt);
        if (batched) {
            softmax_fused<<<S_, 256, 0, stream>>>(
                scores, P + (size_t)b * H_ * S_ * S_, (long)S_ * S_, S_,
                avgw + (size_t)b * S_ * S_, rowsum + (size_t)b * S_);
        } else {
            // P bf16 in place over the fp32 scores rows (row stride 2S)
            softmax_fused<<<S_, 256, 0, stream>>>(
                scores, (bf16*)scores, 2L * S_ * S_, 2 * S_,
                avgw + (size_t)b * S_ * S_, rowsum + (size_t)b * S_);
            mfma_nt<1><<<dim3(HD_ / 128, S_ / 128, H_), 256, 0, stream>>>(
                S_,
                (const bf16*)scores, 2 * S_, 0, 2L * S_ * S_,
                Vtb + (size_t)b * HD_ * S_, S_, 0, (long)B_ * HD_ * S_,
                concat + (size_t)b * S_ * D_, D_, 0, HD_,
                H_, 0, nullptr, nullptr, nullptr, nullptr, nullptr);
        }
    }
    if (batched) {
        // attended = P.V for all (b,h): deep-pipelined counted-vmcnt kernel
        mfma_pv<<<256, 512, 0, stream>>>(P, Vtb, concat);
    }

    // out = concat @ Wo^T (MFMA, bf16 Wo)
    mfma_nt<0><<<dim3(D_ / 128, (B_ * S_) / 128, 1), 256, 0, stream>>>(
        D_, concat, D_, 0, 0, Wob, D_, 0, 0, outp, D_, 0, 0,
        1, 0, nullptr, nullptr, nullptr, nullptr, nullptr);

    ln_kernel<<<B_ * S_, 256, 0, stream>>>(outp, emb, Wo_b, ln_g, ln_bt);
    guilt_kernel<<<B_, 256, 0, stream>>>(rowsum, guilt);
}